// Round 4
// baseline (211.324 us; speedup 1.0000x reference)
//
#include <hip/hip_runtime.h>

// YOLOv1-style loss: S=7, B=2, C=20, L=49, n=16384.
// preds row: [ pcls: 980 | pconf: 98 | pbox: 392 ] = 1470 floats
// labels row: L * [ obj(1) | tcls(20) | tbox(4) ] = 1225 floats
// Weights: NOOBJ=0.5, OBJ=0.5, CLS=0.5, COORD=2.5
//
// R4: coalesced LDS row-staging (2 samples/block) + atomic-free reduction.
// History: R1 scattered loads = 1 TB/s latency-bound (64.7us). R2 staging
// masked by 16384 same-address atomics (222us). R3 = R1 minus atomics
// (~50us est). This round = R2-staging minus atomics, 2 rows/block for MLP.
// LDS 21.6KB -> 7 blocks/CU (87% occ). Floor: 177MB / 6.3TB/s = 28us.

#define L_CELLS 49
#define PRED_ROW 1470
#define LAB_ROW 1225
#define CONF_BASE 980
#define BOX_BASE 1078
#define W_NOOBJ 0.5f
#define W_OBJ 0.5f
#define W_CLS 0.5f
#define W_COORD 2.5f
#define INV_S (1.0f / 7.0f)
#define SPB 2

__global__ __launch_bounds__(256) void yolo_loss_kernel(
    const float* __restrict__ preds, const float* __restrict__ labels,
    float* __restrict__ ws, int n) {
  __shared__ float4 lab4[SPB][308];   // 3-float max lead-in + 1225 floats
  __shared__ float4 pred4[SPB][368];  // 2-float max lead-in + 1470 floats

  const int tid = threadIdx.x;
  const int s0 = blockIdx.x * SPB;

  const size_t ltotal = (size_t)n * LAB_ROW;
  const size_t ptotal = (size_t)n * PRED_ROW;

  // ---- stage SPB label rows + SPB pred rows, all loads issued pre-barrier.
  // Address clamp instead of guards: clamp can only trigger on pad slots of
  // the final rows (row ends coincide with array end), which are never read.
  int loff[SPB], poff[SPB];
#pragma unroll
  for (int r = 0; r < SPB; ++r) {
    size_t lrow = (size_t)(s0 + r) * LAB_ROW;
    size_t lstart = lrow & ~(size_t)3;  // 16B align-down
    loff[r] = (int)(lrow - lstart);
    for (int i = tid; i < 308; i += 256) {
      size_t g = lstart + 4 * (size_t)i;
      if (g > ltotal - 4) g = ltotal - 4;
      lab4[r][i] = *(const float4*)(labels + g);
    }
    size_t prow = (size_t)(s0 + r) * PRED_ROW;
    size_t pstart = prow & ~(size_t)3;
    poff[r] = (int)(prow - pstart);
    for (int i = tid; i < 368; i += 256) {
      size_t g = pstart + 4 * (size_t)i;
      if (g > ptotal - 4) g = ptotal - 4;
      pred4[r][i] = *(const float4*)(preds + g);
    }
  }
  __syncthreads();

  float acc = 0.0f;

#pragma unroll
  for (int r = 0; r < SPB; ++r) {
    const float* lab = (const float*)lab4[r] + loff[r];  // lab[l*25 + k]
    const float* pr = (const float*)pred4[r] + poff[r];  // pred-row index

    // ---- cls term: 980 elements over 256 threads ----
    for (int idx = tid; idx < CONF_BASE; idx += 256) {
      int l = idx / 20;
      int c = idx - l * 20;
      if (lab[l * 25] != 0.0f) {
        float d = lab[l * 25 + 1 + c] - pr[idx];
        acc += W_CLS * d * d;
      }
    }

    // ---- per-cell conf + coord, threads 0..48 ----
    if (tid < L_CELLS) {
      int l = tid;
      float objf = lab[l * 25];
      float c0 = pr[CONF_BASE + 2 * l];
      float c1 = pr[CONF_BASE + 2 * l + 1];
      if (objf != 0.0f) {
        float bx[8];
#pragma unroll
        for (int k = 0; k < 8; ++k) bx[k] = pr[BOX_BASE + 8 * l + k];
        float tx = lab[l * 25 + 21], ty = lab[l * 25 + 22];
        float tw = lab[l * 25 + 23], th = lab[l * 25 + 24];
        float t0 = tx * INV_S, t1 = ty * INV_S, t2 = tw, t3 = th;

        float iou[2], rmse2[2];
#pragma unroll
        for (int b = 0; b < 2; ++b) {
          float o0 = bx[4 * b + 0] * INV_S;
          float o1 = bx[4 * b + 1] * INV_S;
          float o2 = bx[4 * b + 2] * bx[4 * b + 2];
          float o3 = bx[4 * b + 3] * bx[4 * b + 3];
          float left = fmaxf(t0 - 0.5f * t2, o0 - 0.5f * o2);
          float right = fminf(t0 + 0.5f * t2, o0 + 0.5f * o2);
          float top = fmaxf(t1 - 0.5f * t3, o1 - 0.5f * o3);
          float bot = fminf(t1 + 0.5f * t3, o1 + 0.5f * o3);
          float w = right - left;
          float h = bot - top;
          bool invalid = (w < 0.0f) || (h < 0.0f);
          float inter = invalid ? 0.0f : w * h;
          float uni = t2 * t3 + o2 * o3 - inter;
          iou[b] = invalid ? 0.0f : inter / fmaxf(uni, 1e-12f);
          float d0 = t0 - o0, d1 = t1 - o1, d2 = t2 - o2, d3 = t3 - o3;
          rmse2[b] = d0 * d0 + d1 * d1 + d2 * d2 + d3 * d3;  // sqrt monotone
        }

        float max_iou = fmaxf(iou[0], iou[1]);
        // jnp.argmax/argmin: first index wins ties -> strict cmp for idx 1
        int best;
        if (max_iou > 0.0f)
          best = (iou[1] > iou[0]) ? 1 : 0;
        else
          best = (rmse2[1] < rmse2[0]) ? 1 : 0;
        float best_iou = iou[best];

        float cb = (best == 0) ? c0 : c1;
        float co = (best == 0) ? c1 : c0;
        float db = best_iou - cb;
        acc += W_OBJ * db * db + W_NOOBJ * co * co;

        float e0 = tx - bx[best * 4 + 0];
        float e1 = ty - bx[best * 4 + 1];
        float e2 = sqrtf(tw) - bx[best * 4 + 2];
        float e3 = sqrtf(th) - bx[best * 4 + 3];
        acc += W_COORD * (e0 * e0 + e1 * e1 + e2 * e2 + e3 * e3);
      } else {
        acc += W_NOOBJ * (c0 * c0 + c1 * c1);
      }
    }
  }

  // ---- reduce: wave(64) shuffle -> LDS -> one ws slot per block ----
#pragma unroll
  for (int off = 32; off > 0; off >>= 1) acc += __shfl_down(acc, off);

  __shared__ float wsum[4];
  int wave = tid >> 6;
  int lane = tid & 63;
  if (lane == 0) wsum[wave] = acc;
  __syncthreads();
  if (tid == 0) ws[blockIdx.x] = wsum[0] + wsum[1] + wsum[2] + wsum[3];
}

__global__ __launch_bounds__(256) void final_reduce_kernel(
    const float* __restrict__ ws, float* __restrict__ out, int m) {
  float acc = 0.0f;
  for (int i = threadIdx.x; i < m; i += 256) acc += ws[i];
#pragma unroll
  for (int off = 32; off > 0; off >>= 1) acc += __shfl_down(acc, off);
  __shared__ float wsum[4];
  int wave = threadIdx.x >> 6;
  int lane = threadIdx.x & 63;
  if (lane == 0) wsum[wave] = acc;
  __syncthreads();
  if (threadIdx.x == 0) out[0] = wsum[0] + wsum[1] + wsum[2] + wsum[3];
}

extern "C" void kernel_launch(void* const* d_in, const int* in_sizes, int n_in,
                              void* d_out, int out_size, void* d_ws, size_t ws_size,
                              hipStream_t stream) {
  const float* preds = (const float*)d_in[0];
  const float* labels = (const float*)d_in[1];
  float* out = (float*)d_out;
  float* ws = (float*)d_ws;
  int n = in_sizes[0] / PRED_ROW;  // 16384
  int blocks = n / SPB;            // 8192

  yolo_loss_kernel<<<blocks, 256, 0, stream>>>(preds, labels, ws, n);
  final_reduce_kernel<<<1, 256, 0, stream>>>(ws, out, blocks);
}

// Round 5
// 189.059 us; speedup vs baseline: 1.1178x; 1.1178x over previous
//
#include <hip/hip_runtime.h>

// YOLOv1-style loss: S=7, B=2, C=20, L=49, n=16384.
// preds row: [ pcls: 980 | pconf: 98 | pbox: 392 ] = 1470 floats
// labels row: L * [ obj(1) | tcls(20) | tbox(4) ] = 1225 floats
// Weights: NOOBJ=0.5, OBJ=0.5, CLS=0.5, COORD=2.5
//
// R5: wave-per-sample. Stage ONLY labels (the scatter-hostile array: obj
// flags at stride 100B touch every line anyway) into wave-private LDS with
// coalesced float4 loads -> NO __syncthreads, no block-wide vmcnt drain
// (R4's killer). Preds read direct from global R3-style: conf float2, box
// 4x float2, cls 10x obj-masked float2 (base s*1470+20l is even -> 8B
// aligned). No int divides, no address clamps (<=12B page-safe overread on
// the last row only). LDS 19.9KB -> 8 blocks/CU, 32 waves/CU.

#define L_CELLS 49
#define PRED_ROW 1470
#define LAB_ROW 1225
#define CONF_BASE 980
#define BOX_BASE 1078
#define W_NOOBJ 0.5f
#define W_OBJ 0.5f
#define W_CLS 0.5f
#define W_COORD 2.5f
#define INV_S (1.0f / 7.0f)

__global__ __launch_bounds__(256) void yolo_loss_kernel(
    const float* __restrict__ preds, const float* __restrict__ labels,
    float* __restrict__ ws) {
  __shared__ float4 labs4[4][312];  // 4 waves x (3 lead-in + 1225 + pad)

  const int tid = threadIdx.x;
  const int w = tid >> 6;
  const int lane = tid & 63;
  const int s = blockIdx.x * 4 + w;

  // ---- stage this wave's labels row, coalesced float4 (wave-private LDS,
  // intra-wave lgkmcnt ordering suffices; no barrier) ----
  size_t g0 = (size_t)s * LAB_ROW;
  size_t a = g0 & ~(size_t)3;  // 16B align-down
  int off = (int)(g0 - a);
  for (int i = lane; i < 307; i += 64) {
    labs4[w][i] = *(const float4*)(labels + a + 4 * (size_t)i);
  }

  const float* lab = (const float*)labs4[w] + off;  // lab[25*l + k]
  const float* rp = preds + (size_t)s * PRED_ROW;

  float acc = 0.0f;
  if (lane < L_CELLS) {
    const int l = lane;
    float2 cf = *(const float2*)(rp + CONF_BASE + 2 * l);  // 8B aligned
    float c0 = cf.x, c1 = cf.y;
    float objf = lab[25 * l];

    if (objf != 0.0f) {
      // ---- obj path (~15% of lanes; wave takes it nearly always) ----
      float bx[8];
#pragma unroll
      for (int k = 0; k < 4; ++k) {
        float2 v = *(const float2*)(rp + BOX_BASE + 8 * l + 2 * k);
        bx[2 * k] = v.x;
        bx[2 * k + 1] = v.y;
      }
      float tx = lab[25 * l + 21], ty = lab[25 * l + 22];
      float tw = lab[25 * l + 23], th = lab[25 * l + 24];
      float t0 = tx * INV_S, t1 = ty * INV_S, t2 = tw, t3 = th;

      float iou[2], rmse2[2];
#pragma unroll
      for (int b = 0; b < 2; ++b) {
        float o0 = bx[4 * b + 0] * INV_S;
        float o1 = bx[4 * b + 1] * INV_S;
        float o2 = bx[4 * b + 2] * bx[4 * b + 2];
        float o3 = bx[4 * b + 3] * bx[4 * b + 3];
        float left = fmaxf(t0 - 0.5f * t2, o0 - 0.5f * o2);
        float right = fminf(t0 + 0.5f * t2, o0 + 0.5f * o2);
        float top = fmaxf(t1 - 0.5f * t3, o1 - 0.5f * o3);
        float bot = fminf(t1 + 0.5f * t3, o1 + 0.5f * o3);
        float wd = right - left;
        float h = bot - top;
        bool invalid = (wd < 0.0f) || (h < 0.0f);
        float inter = invalid ? 0.0f : wd * h;
        float uni = t2 * t3 + o2 * o3 - inter;
        iou[b] = invalid ? 0.0f : inter / fmaxf(uni, 1e-12f);
        float d0 = t0 - o0, d1 = t1 - o1, d2 = t2 - o2, d3 = t3 - o3;
        rmse2[b] = d0 * d0 + d1 * d1 + d2 * d2 + d3 * d3;  // sqrt monotone
      }

      float max_iou = fmaxf(iou[0], iou[1]);
      // jnp.argmax/argmin: first index wins ties -> strict compare for idx 1
      int best;
      if (max_iou > 0.0f)
        best = (iou[1] > iou[0]) ? 1 : 0;
      else
        best = (rmse2[1] < rmse2[0]) ? 1 : 0;
      float best_iou = iou[best];

      float cb = (best == 0) ? c0 : c1;
      float co = (best == 0) ? c1 : c0;
      float db = best_iou - cb;
      acc += W_OBJ * db * db + W_NOOBJ * co * co;

      // cls: 10 float2 gathers (always 8B aligned), tcls from LDS
      float clsacc = 0.0f;
#pragma unroll
      for (int k = 0; k < 10; ++k) {
        float2 p = *(const float2*)(rp + 20 * l + 2 * k);
        float d0 = lab[25 * l + 1 + 2 * k] - p.x;
        float d1 = lab[25 * l + 2 + 2 * k] - p.y;
        clsacc += d0 * d0 + d1 * d1;
      }
      acc += W_CLS * clsacc;

      // coord: (tx, ty, sqrt(tw), sqrt(th)) vs best raw box
      float e0 = tx - bx[best * 4 + 0];
      float e1 = ty - bx[best * 4 + 1];
      float e2 = sqrtf(tw) - bx[best * 4 + 2];
      float e3 = sqrtf(th) - bx[best * 4 + 3];
      acc += W_COORD * (e0 * e0 + e1 * e1 + e2 * e2 + e3 * e3);
    } else {
      acc += W_NOOBJ * (c0 * c0 + c1 * c1);
    }
  }

  // ---- reduce: wave(64) shuffle -> LDS -> one ws slot per block ----
#pragma unroll
  for (int o = 32; o > 0; o >>= 1) acc += __shfl_down(acc, o);

  __shared__ float wsum[4];
  if (lane == 0) wsum[w] = acc;
  __syncthreads();
  if (tid == 0) ws[blockIdx.x] = wsum[0] + wsum[1] + wsum[2] + wsum[3];
}

__global__ __launch_bounds__(256) void final_reduce_kernel(
    const float* __restrict__ ws, float* __restrict__ out, int m) {
  float acc = 0.0f;
  for (int i = threadIdx.x; i < m; i += 256) acc += ws[i];
#pragma unroll
  for (int o = 32; o > 0; o >>= 1) acc += __shfl_down(acc, o);
  __shared__ float wsum[4];
  int wave = threadIdx.x >> 6;
  int lane = threadIdx.x & 63;
  if (lane == 0) wsum[wave] = acc;
  __syncthreads();
  if (threadIdx.x == 0) out[0] = wsum[0] + wsum[1] + wsum[2] + wsum[3];
}

extern "C" void kernel_launch(void* const* d_in, const int* in_sizes, int n_in,
                              void* d_out, int out_size, void* d_ws, size_t ws_size,
                              hipStream_t stream) {
  const float* preds = (const float*)d_in[0];
  const float* labels = (const float*)d_in[1];
  float* out = (float*)d_out;
  float* ws = (float*)d_ws;
  int n = in_sizes[0] / PRED_ROW;  // 16384
  int blocks = n / 4;              // 4096 (wave per sample, 4 waves/block)

  yolo_loss_kernel<<<blocks, 256, 0, stream>>>(preds, labels, ws);
  final_reduce_kernel<<<1, 256, 0, stream>>>(ws, out, blocks);
}